// Round 1
// 383.340 us; speedup vs baseline: 1.0385x; 1.0385x over previous
//
#include <hip/hip_runtime.h>
#include <math.h>

#define TTOK 16384
#define DD   4096
#define EE   64
#define TM   32            // tokens per block
#define BK   64            // K per staged chunk
#define NCH  (DD / BK)     // 64 chunks

typedef __attribute__((ext_vector_type(8))) short short8;
typedef __attribute__((ext_vector_type(4))) float f32x4;

static __device__ __forceinline__ unsigned short f2bf(float f) {
    unsigned u = __float_as_uint(f);
    u += 0x7FFFu + ((u >> 16) & 1u);          // RTNE
    return (unsigned short)(u >> 16);
}
static __device__ __forceinline__ float bf2f(unsigned short h) {
    return __uint_as_float(((unsigned)h) << 16);
}
// 8 consecutive fp32 -> bf16 hi + bf16 lo (lo = rn(v - hi)); lo*lo dropped in GEMM
static __device__ __forceinline__ void cvt8(float4 a, float4 b, short8& hi, short8& lo) {
    const float v[8] = {a.x, a.y, a.z, a.w, b.x, b.y, b.z, b.w};
#pragma unroll
    for (int j = 0; j < 8; ++j) {
        const unsigned short h = f2bf(v[j]);
        hi[j] = (short)h;
        lo[j] = (short)f2bf(v[j] - bf2f(h));
    }
}

__global__ void w_convert(const float* __restrict__ W,
                          unsigned short* __restrict__ whi,
                          unsigned short* __restrict__ wlo) {
    const int i = (blockIdx.x * blockDim.x + threadIdx.x) * 4;
    if (i >= EE * DD) return;
    const float4 v = *reinterpret_cast<const float4*>(W + i);
    ushort4 h, l;
    h.x = f2bf(v.x); l.x = f2bf(v.x - bf2f(h.x));
    h.y = f2bf(v.y); l.y = f2bf(v.y - bf2f(h.y));
    h.z = f2bf(v.z); l.z = f2bf(v.z - bf2f(h.z));
    h.w = f2bf(v.w); l.w = f2bf(v.w - bf2f(h.w));
    *reinterpret_cast<ushort4*>(whi + i) = h;
    *reinterpret_cast<ushort4*>(wlo + i) = l;
}

// One block = 32 tokens x all 64 experts x K=4096, fully fused with gating.
// 4 waves: wv = tg*2 + eh ; wave computes tokens 16*tg..+16, experts 32*eh..+32.
// Register-prefetch pipeline (1 chunk ahead), LDS rows XOR-swizzled in 16B units.
__global__ __launch_bounds__(256, 2)
void moe_fused(const float* __restrict__ x,
               const unsigned short* __restrict__ whi,
               const unsigned short* __restrict__ wlo,
               float* __restrict__ out)
{
    __shared__ unsigned short xh[TM * 64];   // 4 KB bf16 x hi
    __shared__ unsigned short xl[TM * 64];   // 4 KB bf16 x lo
    __shared__ unsigned short whs[EE * 64];  // 8 KB bf16 W hi
    __shared__ unsigned short wls[EE * 64];  // 8 KB bf16 W lo
    __shared__ float lg[TM * 68];            // logits tile, padded stride

    const int tid  = threadIdx.x;
    const int wv   = tid >> 6;
    const int lane = tid & 63;
    const int m    = lane & 15;
    const int q    = lane >> 4;
    const int tg   = wv >> 1;                // token group 0..1
    const int eh   = wv & 1;                 // expert half 0..1
    const int t0   = blockIdx.x * TM;

    // staging: x -> one row per thread; W -> rows wr and wr+32
    const int sr = tid >> 3;                 // 0..31
    const int sj = tid & 7;
    const int sp  = (sj ^ (sr & 7)) * 8;     // swizzled short offset in row
    const int xo  = sr * 64 + sp;
    const int wo0 = xo;
    const int wo1 = (sr + 32) * 64 + sp;     // (sr+32)&7 == sr&7 -> same swizzle

    const float*          gx  = x   + (size_t)(t0 + sr) * DD + sj * 8;
    const unsigned short* gh0 = whi + (size_t)sr * DD + sj * 8;
    const unsigned short* gh1 = gh0 + (size_t)32 * DD;
    const unsigned short* gl0 = wlo + (size_t)sr * DD + sj * 8;
    const unsigned short* gl1 = gl0 + (size_t)32 * DD;

    f32x4 acc0 = (f32x4){0.f, 0.f, 0.f, 0.f};
    f32x4 acc1 = (f32x4){0.f, 0.f, 0.f, 0.f};

    // prologue: prefetch chunk 0
    float4 fx0  = *reinterpret_cast<const float4*>(gx);
    float4 fx1  = *reinterpret_cast<const float4*>(gx + 4);
    short8 pwh0 = *reinterpret_cast<const short8*>(gh0);
    short8 pwh1 = *reinterpret_cast<const short8*>(gh1);
    short8 pwl0 = *reinterpret_cast<const short8*>(gl0);
    short8 pwl1 = *reinterpret_cast<const short8*>(gl1);

    const int sa  = m & 7;
    const int ra  = (16 * tg + m) * 64;        // A row base (token)
    const int rb0 = (32 * eh + m) * 64;        // B row base, expert tile e=0
    const int rb1 = (32 * eh + 16 + m) * 64;   // expert tile e=1

    for (int kc = 0; kc < NCH; ++kc) {
        __syncthreads();   // previous chunk's frag reads complete
        {
            short8 h, l;
            cvt8(fx0, fx1, h, l);
            *reinterpret_cast<short8*>(xh + xo)   = h;
            *reinterpret_cast<short8*>(xl + xo)   = l;
            *reinterpret_cast<short8*>(whs + wo0) = pwh0;
            *reinterpret_cast<short8*>(whs + wo1) = pwh1;
            *reinterpret_cast<short8*>(wls + wo0) = pwl0;
            *reinterpret_cast<short8*>(wls + wo1) = pwl1;
        }
        __syncthreads();   // staged data visible

        // prefetch chunk kc+1 (drains at next iteration's first barrier)
        if (kc + 1 < NCH) {
            const int off = (kc + 1) * BK;
            fx0  = *reinterpret_cast<const float4*>(gx + off);
            fx1  = *reinterpret_cast<const float4*>(gx + off + 4);
            pwh0 = *reinterpret_cast<const short8*>(gh0 + off);
            pwh1 = *reinterpret_cast<const short8*>(gh1 + off);
            pwl0 = *reinterpret_cast<const short8*>(gl0 + off);
            pwl1 = *reinterpret_cast<const short8*>(gl1 + off);
        }

        // compute chunk kc
#pragma unroll
        for (int kss = 0; kss < 2; ++kss) {
            const int ca = ((4 * kss + q) ^ sa) * 8;
            const short8 ah  = *reinterpret_cast<const short8*>(xh + ra + ca);
            const short8 al  = *reinterpret_cast<const short8*>(xl + ra + ca);
            const short8 bh0 = *reinterpret_cast<const short8*>(whs + rb0 + ca);
            const short8 bl0 = *reinterpret_cast<const short8*>(wls + rb0 + ca);
            const short8 bh1 = *reinterpret_cast<const short8*>(whs + rb1 + ca);
            const short8 bl1 = *reinterpret_cast<const short8*>(wls + rb1 + ca);
            acc0 = __builtin_amdgcn_mfma_f32_16x16x32_bf16(ah, bh0, acc0, 0, 0, 0);
            acc0 = __builtin_amdgcn_mfma_f32_16x16x32_bf16(ah, bl0, acc0, 0, 0, 0);
            acc0 = __builtin_amdgcn_mfma_f32_16x16x32_bf16(al, bh0, acc0, 0, 0, 0);
            acc1 = __builtin_amdgcn_mfma_f32_16x16x32_bf16(ah, bh1, acc1, 0, 0, 0);
            acc1 = __builtin_amdgcn_mfma_f32_16x16x32_bf16(ah, bl1, acc1, 0, 0, 0);
            acc1 = __builtin_amdgcn_mfma_f32_16x16x32_bf16(al, bh1, acc1, 0, 0, 0);
        }
    }

    // accumulators -> LDS logits tile. D layout: row = 4q+i (token), col = m (expert)
    {
        float* lr = lg + (16 * tg + 4 * q) * 68 + 32 * eh + m;
#pragma unroll
        for (int i = 0; i < 4; ++i) {
            lr[i * 68]      = acc0[i];
            lr[i * 68 + 16] = acc1[i];
        }
    }
    __syncthreads();

    // gating: 8 threads per token, thread j owns experts 8j..8j+7
    const int tt = tid >> 3;                 // 0..31
    const int j  = tid & 3 ? (tid & 7) : (tid & 7);  // = tid & 7
    const float* row = lg + tt * 68 + (tid & 7) * 8;
    const int jj = tid & 7;
    const float4 lv0 = *reinterpret_cast<const float4*>(row);
    const float4 lv1 = *reinterpret_cast<const float4*>(row + 4);
    const float r[8] = {lv0.x, lv0.y, lv0.z, lv0.w, lv1.x, lv1.y, lv1.z, lv1.w};
    (void)j;

    // coalesced logits write
    float* gout = out + (size_t)(t0 + tt) * EE + jj * 8;
    *reinterpret_cast<float4*>(gout)     = lv0;
    *reinterpret_cast<float4*>(gout + 4) = lv1;

    // local top-2 (ascending expert order -> lowest index kept on ties)
    float v1 = -INFINITY, v2 = -INFINITY;
    int   i1 = 0, i2 = 0;
#pragma unroll
    for (int c = 0; c < 8; ++c) {
        const int e = jj * 8 + c;
        const float v = r[c];
        if (v > v1)      { v2 = v1; i2 = i1; v1 = v; i1 = e; }
        else if (v > v2) { v2 = v;  i2 = e; }
    }
    // butterfly merge across the 8-lane group (jax tie-break: lower index wins)
#pragma unroll
    for (int mk = 1; mk < 8; mk <<= 1) {
        const float ov1 = __shfl_xor(v1, mk);
        const int   oi1 = __shfl_xor(i1, mk);
        const float ov2 = __shfl_xor(v2, mk);
        const int   oi2 = __shfl_xor(i2, mk);
        const bool aw = (v1 > ov1) || (v1 == ov1 && i1 < oi1);
        const float c1v = aw ? v1 : ov1;  const int c1i = aw ? i1 : oi1;
        const float cav = aw ? v2 : ov2;  const int cai = aw ? i2 : oi2;
        const float cbv = aw ? ov1 : v1;  const int cbi = aw ? oi1 : i1;
        const bool bw = (cav > cbv) || (cav == cbv && cai < cbi);
        v1 = c1v; i1 = c1i;
        v2 = bw ? cav : cbv;
        i2 = bw ? cai : cbi;
    }

    // logsumexp over all 64 experts (v1 is the global max after the butterfly)
    float sm = 0.f;
#pragma unroll
    for (int c = 0; c < 8; ++c) sm += expf(r[c] - v1);
#pragma unroll
    for (int mk = 1; mk < 8; mk <<= 1) sm += __shfl_xor(sm, mk);

    const float logz = v1 + logf(sm);
    if (jj == 0) out[(size_t)2 * TTOK * EE + t0 + tt] = logz * logz;

    // 2-way softmax scores scattered into the 64-expert vector
    const float e21 = expf(v2 - v1);
    const float rr  = 1.f / (1.f + e21);
    const float s1 = rr, s2 = e21 * rr;
    float* sc = out + (size_t)TTOK * EE + (size_t)(t0 + tt) * EE + jj * 8;
    float vv[8];
#pragma unroll
    for (int c = 0; c < 8; ++c) {
        const int e = jj * 8 + c;
        vv[c] = (e == i1) ? s1 : ((e == i2) ? s2 : 0.f);
    }
    *reinterpret_cast<float4*>(sc)     = make_float4(vv[0], vv[1], vv[2], vv[3]);
    *reinterpret_cast<float4*>(sc + 4) = make_float4(vv[4], vv[5], vv[6], vv[7]);
}

extern "C" void kernel_launch(void* const* d_in, const int* in_sizes, int n_in,
                              void* d_out, int out_size, void* d_ws, size_t ws_size,
                              hipStream_t stream) {
    const float* x = (const float*)d_in[0];
    const float* W = (const float*)d_in[1];
    float* out = (float*)d_out;
    unsigned short* whi = (unsigned short*)d_ws;
    unsigned short* wlo = whi + (size_t)EE * DD;

    w_convert<<<dim3((EE * DD / 4 + 255) / 256), dim3(256), 0, stream>>>(W, whi, wlo);
    moe_fused<<<dim3(TTOK / TM), dim3(256), 0, stream>>>(x, whi, wlo, out);
}